// Round 1
// baseline (26027.762 us; speedup 1.0000x reference)
//
#include <hip/hip_runtime.h>
#include <math.h>

// Problem constants
#define BB 16
#define TT 128
#define F_IN 240
#define E_DIM 1024
#define HH 320
#define G4 1280        // 4*H
#define JHD 512
#define VV 29
#define BLANKV 28
#define MAXSYM 3
#define LBUF (TT*MAXSYM) // 384

// Workspace layout (float offsets)
#define OFF_FPROJ 0ul                      // 2048*512 = 1048576
#define OFF_W0T   1048576ul                // 320*1280 = 409600 (blocked [80][1280][4])
#define OFF_W1AT  (OFF_W0T + 409600ul)
#define OFF_W1BT  (OFF_W1AT + 409600ul)
#define OFF_WJHT  (OFF_W1BT + 409600ul)    // 320*512 blocked [80][512][4]
#define OFF_EP    (OFF_WJHT + 163840ul)    // 29*1280
#define OFF_B1    (OFF_EP + 37120ul)       // 1280

__device__ __forceinline__ float sigmoidf(float x) {
    return 1.0f / (1.0f + expf(-x));
}

// ---- Prep: transpose LSTM weights into k-blocked layout + combined bias ----
__global__ void prep_t_kernel(const float* __restrict__ Whh0,
                              const float* __restrict__ Wih1,
                              const float* __restrict__ Whh1,
                              const float* __restrict__ Wj1,
                              const float* __restrict__ bih1,
                              const float* __restrict__ bhh1,
                              float* __restrict__ W0T, float* __restrict__ W1aT,
                              float* __restrict__ W1bT, float* __restrict__ WjhT,
                              float* __restrict__ b1) {
    int idx = blockIdx.x * 256 + threadIdx.x;
    if (idx < 409600) {
        // idx = j*320 + k  (reads coalesced along k)
        int j = idx / 320, k = idx % 320;
        int d = (k >> 2) * (G4 * 4) + j * 4 + (k & 3);
        W0T[d]  = Whh0[idx];
        W1aT[d] = Wih1[idx];
        W1bT[d] = Whh1[idx];
        return;
    }
    int idx2 = idx - 409600;
    if (idx2 < 163840) {
        // Wj1 rows 1024..1343 -> blocked [80][512][4]
        int k = idx2 / 512, j = idx2 % 512;
        WjhT[(k >> 2) * (JHD * 4) + j * 4 + (k & 3)] = Wj1[(size_t)(1024 + k) * JHD + j];
        return;
    }
    int idx3 = idx2 - 163840;
    if (idx3 < G4) b1[idx3] = bih1[idx3] + bhh1[idx3];
}

// ---- Prep: EP[v][j] = embed[v] @ Wih0[j,:] + bih0[j] + bhh0[j]; row 28 = bias only
__global__ void ep_kernel(const float* __restrict__ embed,
                          const float* __restrict__ Wih0,
                          const float* __restrict__ bih0,
                          const float* __restrict__ bhh0,
                          float* __restrict__ EP) {
    __shared__ __align__(16) float es[HH];
    int v = blockIdx.x; // 0..28
    for (int k = threadIdx.x; k < HH; k += 256)
        es[k] = (v < VV - 1) ? embed[v * HH + k] : 0.0f;
    __syncthreads();
    for (int j = threadIdx.x; j < G4; j += 256) {
        float acc = bih0[j] + bhh0[j];
        if (v < VV - 1) {
            const float4* wr = (const float4*)(Wih0 + (size_t)j * HH);
            const float4* ev = (const float4*)es;
            #pragma unroll 4
            for (int k4 = 0; k4 < HH / 4; ++k4) {
                float4 w = wr[k4], e = ev[k4];
                acc += w.x * e.x + w.y * e.y + w.z * e.z + w.w * e.w;
            }
        }
        EP[v * G4 + j] = acc;
    }
}

// ---- Encoder + F_proj fused: 8 rows per block ----
__global__ __launch_bounds__(512) void enc_fproj_kernel(
    const float* __restrict__ x, const float* __restrict__ Wenc,
    const float* __restrict__ benc, const float* __restrict__ Wj1,
    const float* __restrict__ bj1,
    float* __restrict__ logits_out, float* __restrict__ Fproj) {
    __shared__ float xs[8][F_IN];
    __shared__ float ls[8][E_DIM];
    int row0 = blockIdx.x * 8;
    int tid = threadIdx.x;
    for (int i = tid; i < 8 * F_IN; i += 512)
        xs[i / F_IN][i % F_IN] = x[(size_t)row0 * F_IN + i];
    __syncthreads();
    // encoder: logits = x @ Wenc + benc
    for (int j = tid; j < E_DIM; j += 512) {
        float acc[8];
        float bv = benc[j];
        #pragma unroll
        for (int r = 0; r < 8; ++r) acc[r] = bv;
        for (int k = 0; k < F_IN; ++k) {
            float w = Wenc[(size_t)k * E_DIM + j];
            #pragma unroll
            for (int r = 0; r < 8; ++r) acc[r] += xs[r][k] * w;
        }
        #pragma unroll
        for (int r = 0; r < 8; ++r) {
            ls[r][j] = acc[r];
            logits_out[(size_t)(row0 + r) * E_DIM + j] = acc[r];
        }
    }
    __syncthreads();
    // Fproj = logits @ Wj1[:1024] + bj1  (no relu here)
    {
        int j = tid; // 512 threads == 512 outputs
        float acc[8];
        float bv = bj1[j];
        #pragma unroll
        for (int r = 0; r < 8; ++r) acc[r] = bv;
        for (int k = 0; k < E_DIM; ++k) {
            float w = Wj1[(size_t)k * JHD + j];
            #pragma unroll
            for (int r = 0; r < 8; ++r) acc[r] += ls[r][k] * w;
        }
        #pragma unroll
        for (int r = 0; r < 8; ++r) Fproj[(size_t)(row0 + r) * JHD + j] = acc[r];
    }
}

// ---- Greedy decode: one workgroup per batch item ----
__global__ __launch_bounds__(1024) void decode_kernel(
    const int* __restrict__ out_lens,
    const float* __restrict__ Fproj,
    const float* __restrict__ W0T, const float* __restrict__ W1aT,
    const float* __restrict__ W1bT, const float* __restrict__ WjhT,
    const float* __restrict__ EP, const float* __restrict__ b1,
    const float* __restrict__ Wj2, const float* __restrict__ bj2,
    float* __restrict__ out_lens_out, float* __restrict__ labels_out,
    float* __restrict__ counts_out) {
    int b = blockIdx.x;
    int tid = threadIdx.x;

    __shared__ __align__(16) float h0c[HH], c0c[HH], h1c[HH], c1c[HH];
    __shared__ __align__(16) float h0n[HH], c0n[HH], h1n[HH], c1n[HH];
    __shared__ __align__(16) float gates[G4];
    __shared__ __align__(16) float jh[JHD];
    __shared__ float red[VV * 32];
    __shared__ float logit[VV];
    __shared__ int s_last, s_count, s_emit, s_predvalid;

    for (int i = tid; i < HH; i += 1024) {
        h0c[i] = 0.f; c0c[i] = 0.f; h1c[i] = 0.f; c1c[i] = 0.f;
    }
    for (int i = tid; i < LBUF; i += 1024)
        labels_out[(size_t)b * LBUF + i] = -1.0f;
    if (tid == 0) {
        s_last = BLANKV;       // EP row 28 = bias-only (SOS, e=0)
        s_count = 0;
        s_predvalid = 0;
        out_lens_out[b] = (float)out_lens[b];
    }
    int L = out_lens[b];
    __syncthreads();

    const int j1 = tid;
    const bool dual = (tid < G4 - 1024);  // threads 0..255 own a second output
    const int j2 = 1024 + tid;

    for (int t = 0; t < L; ++t) {
        int s = 0;
        while (true) {
            if (!s_predvalid) {
                // ---- LSTM cell 0: gates = EP[last] + h0c @ Whh0^T ----
                {
                    const float* ep = EP + (size_t)s_last * G4;
                    float acc1 = ep[j1];
                    float acc2 = dual ? ep[j2] : 0.f;
                    const float4* xv = (const float4*)h0c;
                    #pragma unroll 4
                    for (int kb = 0; kb < HH / 4; ++kb) {
                        float4 xk = xv[kb];
                        float4 w1 = *(const float4*)(W0T + ((size_t)kb * G4 + j1) * 4);
                        acc1 += xk.x * w1.x + xk.y * w1.y + xk.z * w1.z + xk.w * w1.w;
                        if (dual) {
                            float4 w2 = *(const float4*)(W0T + ((size_t)kb * G4 + j2) * 4);
                            acc2 += xk.x * w2.x + xk.y * w2.y + xk.z * w2.z + xk.w * w2.w;
                        }
                    }
                    gates[j1] = acc1;
                    if (dual) gates[j2] = acc2;
                }
                __syncthreads();
                if (tid < HH) {
                    float ig = sigmoidf(gates[tid]);
                    float fg = sigmoidf(gates[HH + tid]);
                    float gg = tanhf(gates[2 * HH + tid]);
                    float og = sigmoidf(gates[3 * HH + tid]);
                    float c = fg * c0c[tid] + ig * gg;
                    c0n[tid] = c;
                    h0n[tid] = og * tanhf(c);
                }
                __syncthreads();
                // ---- LSTM cell 1: gates = b1 + h0n @ Wih1^T + h1c @ Whh1^T ----
                {
                    float acc1 = b1[j1];
                    float acc2 = dual ? b1[j2] : 0.f;
                    const float4* xa = (const float4*)h0n;
                    const float4* xb = (const float4*)h1c;
                    #pragma unroll 4
                    for (int kb = 0; kb < HH / 4; ++kb) {
                        float4 xA = xa[kb], xB = xb[kb];
                        float4 wa = *(const float4*)(W1aT + ((size_t)kb * G4 + j1) * 4);
                        float4 wb = *(const float4*)(W1bT + ((size_t)kb * G4 + j1) * 4);
                        acc1 += xA.x * wa.x + xA.y * wa.y + xA.z * wa.z + xA.w * wa.w;
                        acc1 += xB.x * wb.x + xB.y * wb.y + xB.z * wb.z + xB.w * wb.w;
                        if (dual) {
                            float4 wa2 = *(const float4*)(W1aT + ((size_t)kb * G4 + j2) * 4);
                            float4 wb2 = *(const float4*)(W1bT + ((size_t)kb * G4 + j2) * 4);
                            acc2 += xA.x * wa2.x + xA.y * wa2.y + xA.z * wa2.z + xA.w * wa2.w;
                            acc2 += xB.x * wb2.x + xB.y * wb2.y + xB.z * wb2.z + xB.w * wb2.w;
                        }
                    }
                    gates[j1] = acc1;
                    if (dual) gates[j2] = acc2;
                }
                __syncthreads();
                if (tid < HH) {
                    float ig = sigmoidf(gates[tid]);
                    float fg = sigmoidf(gates[HH + tid]);
                    float gg = tanhf(gates[2 * HH + tid]);
                    float og = sigmoidf(gates[3 * HH + tid]);
                    float c = fg * c1c[tid] + ig * gg;
                    c1n[tid] = c;
                    h1n[tid] = og * tanhf(c);
                }
                if (tid == 0) s_predvalid = 1;
                __syncthreads();
            }
            // ---- Joint: jh = relu(Fproj[b,t] + h1n @ Wj1h); logits = jh @ Wj2 + bj2
            if (tid < JHD) {
                float acc = Fproj[((size_t)b * TT + t) * JHD + tid];
                const float4* xv = (const float4*)h1n;
                #pragma unroll 4
                for (int kb = 0; kb < HH / 4; ++kb) {
                    float4 xk = xv[kb];
                    float4 w = *(const float4*)(WjhT + ((size_t)kb * JHD + tid) * 4);
                    acc += xk.x * w.x + xk.y * w.y + xk.z * w.z + xk.w * w.w;
                }
                jh[tid] = fmaxf(acc, 0.f);
            }
            __syncthreads();
            if (tid < VV * 32) {
                int v = tid >> 5, sl = tid & 31;
                float acc = 0.f;
                #pragma unroll 4
                for (int j = sl; j < JHD; j += 32) acc += jh[j] * Wj2[(size_t)j * VV + v];
                red[tid] = acc;
            }
            __syncthreads();
            if (tid < VV) {
                float acc = bj2[tid];
                #pragma unroll
                for (int p = 0; p < 32; ++p) acc += red[tid * 32 + p];
                logit[tid] = acc;
            }
            __syncthreads();
            if (tid == 0) {
                int k = 0; float best = logit[0];
                for (int v = 1; v < VV; ++v)
                    if (logit[v] > best) { best = logit[v]; k = v; }
                if (k == BLANKV) {
                    s_emit = 0;
                } else {
                    s_emit = 1;
                    labels_out[(size_t)b * LBUF + s_count] = (float)k;
                    s_count++;
                    s_last = k;
                    s_predvalid = 0;
                }
            }
            __syncthreads();
            if (s_emit) {
                for (int i = tid; i < HH; i += 1024) {
                    h0c[i] = h0n[i]; c0c[i] = c0n[i];
                    h1c[i] = h1n[i]; c1c[i] = c1n[i];
                }
                __syncthreads();
                s++;
                if (s == MAXSYM) break;
            } else {
                break;
            }
        }
    }
    if (tid == 0) counts_out[b] = (float)s_count;
}

extern "C" void kernel_launch(void* const* d_in, const int* in_sizes, int n_in,
                              void* d_out, int out_size, void* d_ws, size_t ws_size,
                              hipStream_t stream) {
    const float* x      = (const float*)d_in[0];
    const int*   lens   = (const int*)d_in[1];
    const float* Wenc   = (const float*)d_in[2];
    const float* benc   = (const float*)d_in[3];
    const float* embed  = (const float*)d_in[4];
    const float* Wih0   = (const float*)d_in[5];
    const float* Whh0   = (const float*)d_in[6];
    const float* bih0   = (const float*)d_in[7];
    const float* bhh0   = (const float*)d_in[8];
    const float* Wih1   = (const float*)d_in[9];
    const float* Whh1   = (const float*)d_in[10];
    const float* bih1   = (const float*)d_in[11];
    const float* bhh1   = (const float*)d_in[12];
    const float* Wj1    = (const float*)d_in[13];
    const float* bj1    = (const float*)d_in[14];
    const float* Wj2    = (const float*)d_in[15];
    const float* bj2    = (const float*)d_in[16];

    float* out = (float*)d_out;
    float* logits_out   = out;                         // [B*T*E_DIM]
    float* out_lens_out = out + (size_t)BB * TT * E_DIM;
    float* labels_out   = out_lens_out + BB;           // [B*384]
    float* counts_out   = labels_out + (size_t)BB * LBUF;

    float* ws = (float*)d_ws;
    float* Fproj = ws + OFF_FPROJ;
    float* W0T   = ws + OFF_W0T;
    float* W1aT  = ws + OFF_W1AT;
    float* W1bT  = ws + OFF_W1BT;
    float* WjhT  = ws + OFF_WJHT;
    float* EP    = ws + OFF_EP;
    float* b1    = ws + OFF_B1;

    // prep: transposes + combined bias
    {
        int total = 409600 + 163840 + G4;
        int blocks = (total + 255) / 256;
        prep_t_kernel<<<blocks, 256, 0, stream>>>(Whh0, Wih1, Whh1, Wj1, bih1, bhh1,
                                                  W0T, W1aT, W1bT, WjhT, b1);
    }
    ep_kernel<<<VV, 256, 0, stream>>>(embed, Wih0, bih0, bhh0, EP);
    enc_fproj_kernel<<<(BB * TT) / 8, 512, 0, stream>>>(x, Wenc, benc, Wj1, bj1,
                                                        logits_out, Fproj);
    decode_kernel<<<BB, 1024, 0, stream>>>(lens, Fproj, W0T, W1aT, W1bT, WjhT,
                                           EP, b1, Wj2, bj2,
                                           out_lens_out, labels_out, counts_out);
}